// Round 5
// baseline (393.468 us; speedup 1.0000x reference)
//
#include <hip/hip_runtime.h>

// ConvTranspose3d(3->16,k=3,s=2,p=1) + per-channel BN-norm + 2x avgpool2, fully fused.
// Identity 1: pooled output = stride-2 3^3 conv of x with collapsed kernel G.
// Identity 2: sum(y) and sum(y^2) (per co, over n+space) via x-autocorrelation at
// 27 lags + inclusion-exclusion boundary corrections (faces/edges/corners).

#define I3 32768
#define NS 98304              // n stride in x = 3*32768
#define COUNT_Y 8001504.0f    // 32*63^3
#define POOL3 3375
#define TOTAL_OUT 1728000

// ws layout (floats)
#define WS_G    0      // 1296
#define WS_A3P  1296   // 243*32
#define WS_X3P  9072   // 3*32
#define WS_A2   9168   // 486
#define WS_X2   9654   // 18
#define WS_A1   9672   // 324
#define WS_X1   9996   // 36
#define WS_AB   10032  // 32

// ---------- collapsed pool kernel G[ci][co][j] ----------
__global__ void prep_G(const float* __restrict__ w, float* __restrict__ G) {
    const int idx = blockIdx.x * 256 + threadIdx.x;
    if (idx >= 1296) return;
    const int ci = idx / 432, rem = idx % 432, co = rem / 27, j = rem % 27;
    const int jd = j / 9, jh = (j / 3) % 3, jw = j % 3;
    const int SLEN[3] = {2, 3, 1};
    const int SK[3][3] = {{1, 2, 0}, {0, 1, 2}, {0, 0, 0}};
    const float* wp = w + (ci * 16 + co) * 27;
    float s = 0.f;
    for (int a = 0; a < SLEN[jd]; ++a)
        for (int b = 0; b < SLEN[jh]; ++b)
            for (int c = 0; c < SLEN[jw]; ++c)
                s += wp[SK[jd][a] * 9 + SK[jh][b] * 3 + SK[jw][c]];
    G[idx] = s;
}

// ---------- pooled conv: P[n,co,p] = sum_{ci,j} G*x[2p+j], all interior ----------
__global__ __launch_bounds__(256, 4) void pooled_conv(
    const float* __restrict__ x, const float* __restrict__ G,
    float* __restrict__ pool) {
    const int pd = blockIdx.x >> 1, coh = blockIdx.x & 1, n = blockIdx.y;
    const int tid = threadIdx.x;
    if (tid >= 225) return;
    const int ph = tid / 15, pw = tid % 15;
    const float* xn = x + (size_t)n * NS;
    float acc[8] = {};
    #pragma unroll
    for (int ci = 0; ci < 3; ++ci) {
        float xl[27];
        const float* xc = xn + ci * I3 + (2 * pd) * 1024 + (2 * ph) * 32 + 2 * pw;
        #pragma unroll
        for (int jd = 0; jd < 3; ++jd)
            #pragma unroll
            for (int jh = 0; jh < 3; ++jh) {
                const float* r = xc + jd * 1024 + jh * 32;
                const float2 f2 = *reinterpret_cast<const float2*>(r);
                xl[jd * 9 + jh * 3 + 0] = f2.x;
                xl[jd * 9 + jh * 3 + 1] = f2.y;
                xl[jd * 9 + jh * 3 + 2] = r[2];
            }
        #pragma unroll
        for (int c8 = 0; c8 < 8; ++c8) {
            const float* gp = G + (ci * 16 + coh * 8 + c8) * 27;
            #pragma unroll
            for (int j = 0; j < 27; ++j)
                acc[c8] = fmaf(gp[j], xl[j], acc[c8]);
        }
    }
    const int ob = (n * 16 + coh * 8) * POOL3 + pd * 225 + ph * 15 + pw;
    #pragma unroll
    for (int c8 = 0; c8 < 8; ++c8) pool[ob + c8 * POOL3] = acc[c8];
}

// ---------- 3D autocorrelation A3[pair][dd][dh][dw], full-support ----------
__global__ __launch_bounds__(256, 4) void autocorr3d(
    const float* __restrict__ x, float* __restrict__ A3p, float* __restrict__ X3p) {
    const int bx = blockIdx.x;          // 27 = pd9*3 + (dd+1)
    const int n  = blockIdx.y;
    const int pd9 = bx / 3, dd = bx % 3 - 1;
    const int ci = pd9 / 3, cj = pd9 % 3;
    const int tid = threadIdx.x;
    const int id = tid >> 3, ihc = tid & 7;
    const float* bi = x + (size_t)n * NS + ci * I3 + id * 1024;
    const int idj = id + dd;
    const bool vd = ((unsigned)idj < 32u);
    const float* bj = x + (size_t)n * NS + cj * I3 + idj * 1024;
    const bool dodiag = (ci == cj) && (dd == 0);

    float acc[3][3] = {};
    float xs = 0.f;
    #pragma unroll
    for (int r = 0; r < 4; ++r) {
        const int ih = ihc + r * 8;
        float own[32];
        #pragma unroll
        for (int q = 0; q < 8; ++q) {
            const float4 f = *reinterpret_cast<const float4*>(bi + ih * 32 + q * 4);
            own[q * 4 + 0] = f.x; own[q * 4 + 1] = f.y;
            own[q * 4 + 2] = f.z; own[q * 4 + 3] = f.w;
        }
        if (dodiag) {
            #pragma unroll
            for (int v = 0; v < 32; ++v) xs += own[v];
        }
        if (vd) {
            #pragma unroll
            for (int dh = -1; dh <= 1; ++dh) {
                const int ihj = ih + dh;
                if ((unsigned)ihj < 32u) {
                    float nb[32];
                    #pragma unroll
                    for (int q = 0; q < 8; ++q) {
                        const float4 f = *reinterpret_cast<const float4*>(bj + ihj * 32 + q * 4);
                        nb[q * 4 + 0] = f.x; nb[q * 4 + 1] = f.y;
                        nb[q * 4 + 2] = f.z; nb[q * 4 + 3] = f.w;
                    }
                    float a0 = 0.f, a1 = 0.f, a2 = 0.f;
                    #pragma unroll
                    for (int v = 0; v < 32; ++v) a1 = fmaf(own[v], nb[v], a1);
                    #pragma unroll
                    for (int v = 0; v < 31; ++v) a2 = fmaf(own[v], nb[v + 1], a2);
                    #pragma unroll
                    for (int v = 1; v < 32; ++v) a0 = fmaf(own[v], nb[v - 1], a0);
                    acc[dh + 1][0] += a0; acc[dh + 1][1] += a1; acc[dh + 1][2] += a2;
                }
            }
        }
    }
    #pragma unroll
    for (int m = 1; m < 64; m <<= 1) {
        #pragma unroll
        for (int a = 0; a < 3; ++a)
            #pragma unroll
            for (int b = 0; b < 3; ++b)
                acc[a][b] += __shfl_xor(acc[a][b], m, 64);
        xs += __shfl_xor(xs, m, 64);
    }
    __shared__ float red[4][10];
    const int wave = tid >> 6, lane = tid & 63;
    if (lane == 0) {
        #pragma unroll
        for (int a = 0; a < 3; ++a)
            #pragma unroll
            for (int b = 0; b < 3; ++b) red[wave][a * 3 + b] = acc[a][b];
        red[wave][9] = xs;
    }
    __syncthreads();
    if (tid < 9)
        A3p[(bx * 9 + tid) * 32 + n] = red[0][tid] + red[1][tid] + red[2][tid] + red[3][tid];
    if (dodiag && tid == 9)
        X3p[ci * 32 + n] = red[0][9] + red[1][9] + red[2][9] + red[3][9];
}

// ---------- face (2D) autocorrs: A2[f][pair][du][dv], X2[f][ci] ----------
__global__ __launch_bounds__(256, 2) void faces_k(
    const float* __restrict__ x, float* __restrict__ A2, float* __restrict__ X2) {
    const int b = blockIdx.x;           // 54 = f*9 + pd9
    const int f = b / 9, pd9 = b % 9;
    const int s = f >> 1, e = (f & 1) ? 31 : 0;
    const int ci = pd9 / 3, cj = pd9 % 3;
    int su, sv, off;
    if (s == 0)      { su = 32;   sv = 1;  off = e * 1024; }  // pin d, free (h,w)
    else if (s == 1) { su = 1024; sv = 1;  off = e * 32;   }  // pin h, free (d,w)
    else             { su = 1024; sv = 32; off = e;        }  // pin w, free (d,h)
    const int tid = threadIdx.x;
    const int n = tid >> 3, uc = tid & 7;
    const float* bi = x + (size_t)n * NS + ci * I3 + off;
    const float* bj = x + (size_t)n * NS + cj * I3 + off;
    const bool dodiag = (ci == cj);

    float acc[3][3] = {};
    float xs = 0.f;
    #pragma unroll
    for (int r = 0; r < 4; ++r) {
        const int u = uc + r * 8;
        float own[32];
        #pragma unroll
        for (int v = 0; v < 32; ++v) own[v] = bi[u * su + v * sv];
        if (dodiag) {
            #pragma unroll
            for (int v = 0; v < 32; ++v) xs += own[v];
        }
        #pragma unroll
        for (int du = -1; du <= 1; ++du) {
            const int uj = u + du;
            if ((unsigned)uj < 32u) {
                float nb[32];
                #pragma unroll
                for (int v = 0; v < 32; ++v) nb[v] = bj[uj * su + v * sv];
                float a0 = 0.f, a1 = 0.f, a2 = 0.f;
                #pragma unroll
                for (int v = 0; v < 32; ++v) a1 = fmaf(own[v], nb[v], a1);
                #pragma unroll
                for (int v = 0; v < 31; ++v) a2 = fmaf(own[v], nb[v + 1], a2);
                #pragma unroll
                for (int v = 1; v < 32; ++v) a0 = fmaf(own[v], nb[v - 1], a0);
                acc[du + 1][0] += a0; acc[du + 1][1] += a1; acc[du + 1][2] += a2;
            }
        }
    }
    #pragma unroll
    for (int m = 1; m < 64; m <<= 1) {
        #pragma unroll
        for (int a = 0; a < 3; ++a)
            #pragma unroll
            for (int b2 = 0; b2 < 3; ++b2)
                acc[a][b2] += __shfl_xor(acc[a][b2], m, 64);
        xs += __shfl_xor(xs, m, 64);
    }
    __shared__ float red[4][10];
    const int wave = tid >> 6, lane = tid & 63;
    if (lane == 0) {
        #pragma unroll
        for (int a = 0; a < 3; ++a)
            #pragma unroll
            for (int b2 = 0; b2 < 3; ++b2) red[wave][a * 3 + b2] = acc[a][b2];
        red[wave][9] = xs;
    }
    __syncthreads();
    if (tid < 9)
        A2[(f * 9 + pd9) * 9 + tid] = red[0][tid] + red[1][tid] + red[2][tid] + red[3][tid];
    if (dodiag && tid == 9)
        X2[f * 3 + ci] = red[0][9] + red[1][9] + red[2][9] + red[3][9];
}

// ---------- edge (1D) autocorrs: A1[e12][pair][dt], X1[e12][ci] ----------
__global__ void edges_k(const float* __restrict__ x,
                        float* __restrict__ A1, float* __restrict__ X1) {
    const int b = blockIdx.x;           // 108 = e12*9 + pd9
    const int e12 = b / 9, pd9 = b % 9;
    const int dp = e12 >> 2;
    const int e1 = ((e12 >> 1) & 1) ? 31 : 0, e2 = (e12 & 1) ? 31 : 0;
    int st, off;
    if (dp == 0)      { st = 1;    off = e1 * 1024 + e2 * 32; } // pin d,h free w
    else if (dp == 1) { st = 32;   off = e1 * 1024 + e2;      } // pin d,w free h
    else              { st = 1024; off = e1 * 32 + e2;        } // pin h,w free d
    const int ci = pd9 / 3, cj = pd9 % 3;
    const int tid = threadIdx.x;
    const int n = tid >> 3, vc = tid & 7;
    const float* bi = x + (size_t)n * NS + ci * I3 + off;
    const float* bj = x + (size_t)n * NS + cj * I3 + off;
    float a[3] = {};
    float xs = 0.f;
    #pragma unroll
    for (int r = 0; r < 4; ++r) {
        const int v = vc + r * 8;
        const float ov = bi[v * st];
        xs += ov;
        #pragma unroll
        for (int d = -1; d <= 1; ++d) {
            const int vj = v + d;
            if ((unsigned)vj < 32u) a[d + 1] = fmaf(ov, bj[vj * st], a[d + 1]);
        }
    }
    #pragma unroll
    for (int m = 1; m < 64; m <<= 1) {
        #pragma unroll
        for (int t = 0; t < 3; ++t) a[t] += __shfl_xor(a[t], m, 64);
        xs += __shfl_xor(xs, m, 64);
    }
    __shared__ float red[4][4];
    const int wave = tid >> 6, lane = tid & 63;
    if (lane == 0) {
        red[wave][0] = a[0]; red[wave][1] = a[1]; red[wave][2] = a[2]; red[wave][3] = xs;
    }
    __syncthreads();
    if (tid < 3)
        A1[(e12 * 9 + pd9) * 3 + tid] = red[0][tid] + red[1][tid] + red[2][tid] + red[3][tid];
    if (ci == cj && tid == 3)
        X1[e12 * 3 + ci] = red[0][3] + red[1][3] + red[2][3] + red[3][3];
}

// ---------- finalize: combine A's with weight-pair sums -> ab ----------
__global__ __launch_bounds__(256) void finalize2(
    const float* __restrict__ x, const float* __restrict__ w,
    const float* __restrict__ gamma, const float* __restrict__ beta,
    const float* __restrict__ ws, float* __restrict__ ab) {
    const int tid = threadIdx.x;
    __shared__ float lw[1296];
    __shared__ float lA3[243], lX3[3], lA2[486], lX2[18], lA1[324], lX1[36];
    __shared__ float lxc[8][3][32];
    __shared__ float lA0[72], lX0[24];
    __shared__ float red2[144], red1[48];

    for (int i = tid; i < 1296; i += 256) lw[i] = w[i];
    for (int i = tid; i < 243; i += 256) {
        const float* p = ws + WS_A3P + i * 32;
        float s = 0.f;
        #pragma unroll
        for (int nn = 0; nn < 32; ++nn) s += p[nn];
        lA3[i] = s;
    }
    if (tid < 3) {
        float s = 0.f;
        for (int nn = 0; nn < 32; ++nn) s += ws[WS_X3P + tid * 32 + nn];
        lX3[tid] = s;
    }
    for (int i = tid; i < 486; i += 256) lA2[i] = ws[WS_A2 + i];
    if (tid < 18) lX2[tid] = ws[WS_X2 + tid];
    for (int i = tid; i < 324; i += 256) lA1[i] = ws[WS_A1 + i];
    if (tid < 36) lX1[tid] = ws[WS_X1 + tid];
    for (int i = tid; i < 768; i += 256) {
        const int c = i / 96, ci = (i / 32) % 3, nn = i % 32;
        const int off = (((c >> 2) & 1) ? 31 : 0) * 1024 +
                        (((c >> 1) & 1) ? 31 : 0) * 32 + ((c & 1) ? 31 : 0);
        lxc[c][ci][nn] = x[(size_t)nn * NS + ci * I3 + off];
    }
    __syncthreads();
    if (tid < 72) {
        const int c = tid / 9, p = tid % 9, ci = p / 3, cj = p % 3;
        float s = 0.f;
        for (int nn = 0; nn < 32; ++nn) s += lxc[c][ci][nn] * lxc[c][cj][nn];
        lA0[tid] = s;
    }
    if (tid >= 72 && tid < 96) {
        const int t = tid - 72, c = t / 3, ci = t % 3;
        float s = 0.f;
        for (int nn = 0; nn < 32; ++nn) s += lxc[c][ci][nn];
        lX0[t] = s;
    }
    __syncthreads();

    // valid-k pairs (k, k'=k-2*delta) per delta index 0..2 (= delta -1,0,+1)
    const int KPn[3] = {1, 3, 1};
    const int KPa[3][3] = {{0, 0, 0}, {0, 1, 2}, {2, 0, 0}};
    const int KPb[3][3] = {{2, 0, 0}, {0, 1, 2}, {0, 0, 0}};

    if (tid < 144) {   // quadratic: per (co, ordered ci-pair)
        const int co = tid / 9, p = tid % 9, ci = p / 3, cj = p % 3;
        const float* wi = lw + (ci * 16 + co) * 27;
        const float* wj = lw + (cj * 16 + co) * 27;
        float tot = 0.f;
        for (int dd = 0; dd < 3; ++dd)
            for (int dh = 0; dh < 3; ++dh)
                for (int dw = 0; dw < 3; ++dw) {
                    float sw = 0.f;
                    for (int a = 0; a < KPn[dd]; ++a)
                        for (int b = 0; b < KPn[dh]; ++b)
                            for (int c = 0; c < KPn[dw]; ++c)
                                sw += wi[KPa[dd][a] * 9 + KPa[dh][b] * 3 + KPa[dw][c]] *
                                      wj[KPb[dd][a] * 9 + KPb[dh][b] * 3 + KPb[dw][c]];
                    tot += lA3[p * 27 + dd * 9 + dh * 3 + dw] * sw;
                }
        for (int f = 0; f < 6; ++f) {
            const int s = f >> 1, c = (f & 1) ? 2 : 0;
            float fsum = 0.f;
            for (int du = 0; du < 3; ++du)
                for (int dv = 0; dv < 3; ++dv) {
                    float sw = 0.f;
                    for (int a = 0; a < KPn[du]; ++a)
                        for (int b = 0; b < KPn[dv]; ++b) {
                            const int ku = KPa[du][a], kup = KPb[du][a];
                            const int kv = KPa[dv][b], kvp = KPb[dv][b];
                            int ii, jj;
                            if (s == 0)      { ii = c * 9 + ku * 3 + kv;  jj = c * 9 + kup * 3 + kvp; }
                            else if (s == 1) { ii = ku * 9 + c * 3 + kv;  jj = kup * 9 + c * 3 + kvp; }
                            else             { ii = ku * 9 + kv * 3 + c;  jj = kup * 9 + kvp * 3 + c; }
                            sw += wi[ii] * wj[jj];
                        }
                    fsum += lA2[(f * 9 + p) * 9 + du * 3 + dv] * sw;
                }
            tot -= fsum;
        }
        for (int e12 = 0; e12 < 12; ++e12) {
            const int dp = e12 >> 2;
            const int c1 = ((e12 >> 1) & 1) ? 2 : 0, c2 = (e12 & 1) ? 2 : 0;
            float esum = 0.f;
            for (int dt = 0; dt < 3; ++dt) {
                float sw = 0.f;
                for (int a = 0; a < KPn[dt]; ++a) {
                    const int kt = KPa[dt][a], ktp = KPb[dt][a];
                    int ii, jj;
                    if (dp == 0)      { ii = c1 * 9 + c2 * 3 + kt; jj = c1 * 9 + c2 * 3 + ktp; }
                    else if (dp == 1) { ii = c1 * 9 + kt * 3 + c2; jj = c1 * 9 + ktp * 3 + c2; }
                    else              { ii = kt * 9 + c1 * 3 + c2; jj = ktp * 9 + c1 * 3 + c2; }
                    sw += wi[ii] * wj[jj];
                }
                esum += lA1[(e12 * 9 + p) * 3 + dt] * sw;
            }
            tot += esum;
        }
        for (int c = 0; c < 8; ++c) {
            const int kk = (((c >> 2) & 1) ? 2 : 0) * 9 +
                           (((c >> 1) & 1) ? 2 : 0) * 3 + ((c & 1) ? 2 : 0);
            tot -= lA0[c * 9 + p] * wi[kk] * wj[kk];
        }
        red2[tid] = tot;
    }
    if (tid >= 144 && tid < 192) {   // linear: per (co, ci)
        const int t = tid - 144, co = t / 3, ci = t % 3;
        const float* wi = lw + (ci * 16 + co) * 27;
        float lw3 = 0.f;
        for (int k = 0; k < 27; ++k) lw3 += wi[k];
        float tot = lX3[ci] * lw3;
        for (int f = 0; f < 6; ++f) {
            const int s = f >> 1, c = (f & 1) ? 2 : 0;
            float l2 = 0.f;
            for (int ku = 0; ku < 3; ++ku)
                for (int kv = 0; kv < 3; ++kv) {
                    const int ii = (s == 0) ? c * 9 + ku * 3 + kv
                                 : (s == 1) ? ku * 9 + c * 3 + kv
                                            : ku * 9 + kv * 3 + c;
                    l2 += wi[ii];
                }
            tot -= lX2[f * 3 + ci] * l2;
        }
        for (int e12 = 0; e12 < 12; ++e12) {
            const int dp = e12 >> 2;
            const int c1 = ((e12 >> 1) & 1) ? 2 : 0, c2 = (e12 & 1) ? 2 : 0;
            float l1 = 0.f;
            for (int kt = 0; kt < 3; ++kt) {
                const int ii = (dp == 0) ? c1 * 9 + c2 * 3 + kt
                             : (dp == 1) ? c1 * 9 + kt * 3 + c2
                                         : kt * 9 + c1 * 3 + c2;
                l1 += wi[ii];
            }
            tot += lX1[e12 * 3 + ci] * l1;
        }
        for (int c = 0; c < 8; ++c) {
            const int kk = (((c >> 2) & 1) ? 2 : 0) * 9 +
                           (((c >> 1) & 1) ? 2 : 0) * 3 + ((c & 1) ? 2 : 0);
            tot -= lX0[c * 3 + ci] * wi[kk];
        }
        red1[t] = tot;
    }
    __syncthreads();
    if (tid < 16) {
        float S2 = 0.f;
        for (int p = 0; p < 9; ++p) S2 += red2[tid * 9 + p];
        const float S1 = red1[tid * 3] + red1[tid * 3 + 1] + red1[tid * 3 + 2];
        const float mean = S1 / COUNT_Y;
        const float var = S2 / COUNT_Y - mean * mean;
        const float invg = rsqrtf(var + 1e-5f) * gamma[tid];
        ab[tid] = invg * (1.0f / 64.0f);
        ab[16 + tid] = beta[tid] - mean * invg;
    }
}

__global__ __launch_bounds__(256) void apply_norm(
    float* __restrict__ out, const float* __restrict__ ab) {
    const int base = (blockIdx.x * 256 + threadIdx.x) * 4;
    if (base >= TOTAL_OUT) return;
    float4 v = *reinterpret_cast<float4*>(out + base);
    float r[4] = {v.x, v.y, v.z, v.w};
    #pragma unroll
    for (int j = 0; j < 4; ++j) {
        const int c = ((base + j) / POOL3) & 15;
        r[j] = fmaf(r[j], ab[c], ab[16 + c]);
    }
    *reinterpret_cast<float4*>(out + base) = make_float4(r[0], r[1], r[2], r[3]);
}

extern "C" void kernel_launch(void* const* d_in, const int* in_sizes, int n_in,
                              void* d_out, int out_size, void* d_ws, size_t ws_size,
                              hipStream_t stream) {
    const float* x     = (const float*)d_in[0];
    const float* w     = (const float*)d_in[1];
    const float* gamma = (const float*)d_in[2];
    const float* beta  = (const float*)d_in[3];
    float* out = (float*)d_out;
    float* ws  = (float*)d_ws;

    prep_G<<<6, 256, 0, stream>>>(w, ws + WS_G);
    pooled_conv<<<dim3(30, 32), 256, 0, stream>>>(x, ws + WS_G, out);
    autocorr3d<<<dim3(27, 32), 256, 0, stream>>>(x, ws + WS_A3P, ws + WS_X3P);
    faces_k<<<54, 256, 0, stream>>>(x, ws + WS_A2, ws + WS_X2);
    edges_k<<<108, 256, 0, stream>>>(x, ws + WS_A1, ws + WS_X1);
    finalize2<<<1, 256, 0, stream>>>(x, w, gamma, beta, ws, ws + WS_AB);
    apply_norm<<<(TOTAL_OUT / 4 + 255) / 256, 256, 0, stream>>>(out, ws + WS_AB);
}

// Round 6
// 267.879 us; speedup vs baseline: 1.4688x; 1.4688x over previous
//
#include <hip/hip_runtime.h>

// ConvTranspose3d(3->16,k=3,s=2,p=1) + per-channel BN-norm + 2x avgpool2, fully fused.
// Identity 1: pooled output = stride-2 3^3 conv of x with collapsed kernel G.
// Identity 2: sum(y), sum(y^2) via x-autocorrelation at 27 lags + inclusion-exclusion
// boundary corrections (same-coordinate faces/edges/corners; only delta=0 in pinned dims).
// R6: faces/edges restructured for parallelism + LDS staging (R5 math unchanged).

#define I3 32768
#define NS 98304              // n stride in x = 3*32768
#define COUNT_Y 8001504.0f    // 32*63^3
#define POOL3 3375
#define TOTAL_OUT 1728000

// ws layout (floats)
#define WS_G    0      // 1296
#define WS_A3P  1296   // 243*32
#define WS_X3P  9072   // 3*32
#define WS_A2P  9168   // 486*32
#define WS_X2P  24720  // 18*32
#define WS_A1   25296  // 324
#define WS_X1   25620  // 36
#define WS_AB   25656  // 32  -> total 25688 floats (~100 KB)

// ---------- collapsed pool kernel G[ci][co][j] ----------
__global__ void prep_G(const float* __restrict__ w, float* __restrict__ G) {
    const int idx = blockIdx.x * 256 + threadIdx.x;
    if (idx >= 1296) return;
    const int ci = idx / 432, rem = idx % 432, co = rem / 27, j = rem % 27;
    const int jd = j / 9, jh = (j / 3) % 3, jw = j % 3;
    const int SLEN[3] = {2, 3, 1};
    const int SK[3][3] = {{1, 2, 0}, {0, 1, 2}, {0, 0, 0}};
    const float* wp = w + (ci * 16 + co) * 27;
    float s = 0.f;
    for (int a = 0; a < SLEN[jd]; ++a)
        for (int b = 0; b < SLEN[jh]; ++b)
            for (int c = 0; c < SLEN[jw]; ++c)
                s += wp[SK[jd][a] * 9 + SK[jh][b] * 3 + SK[jw][c]];
    G[idx] = s;
}

// ---------- pooled conv: P[n,co,p] = sum_{ci,j} G*x[2p+j], all interior ----------
__global__ __launch_bounds__(256, 4) void pooled_conv(
    const float* __restrict__ x, const float* __restrict__ G,
    float* __restrict__ pool) {
    const int pd = blockIdx.x >> 1, coh = blockIdx.x & 1, n = blockIdx.y;
    const int tid = threadIdx.x;
    if (tid >= 225) return;
    const int ph = tid / 15, pw = tid % 15;
    const float* xn = x + (size_t)n * NS;
    float acc[8] = {};
    #pragma unroll
    for (int ci = 0; ci < 3; ++ci) {
        float xl[27];
        const float* xc = xn + ci * I3 + (2 * pd) * 1024 + (2 * ph) * 32 + 2 * pw;
        #pragma unroll
        for (int jd = 0; jd < 3; ++jd)
            #pragma unroll
            for (int jh = 0; jh < 3; ++jh) {
                const float* r = xc + jd * 1024 + jh * 32;
                const float2 f2 = *reinterpret_cast<const float2*>(r);
                xl[jd * 9 + jh * 3 + 0] = f2.x;
                xl[jd * 9 + jh * 3 + 1] = f2.y;
                xl[jd * 9 + jh * 3 + 2] = r[2];
            }
        #pragma unroll
        for (int c8 = 0; c8 < 8; ++c8) {
            const float* gp = G + (ci * 16 + coh * 8 + c8) * 27;
            #pragma unroll
            for (int j = 0; j < 27; ++j)
                acc[c8] = fmaf(gp[j], xl[j], acc[c8]);
        }
    }
    const int ob = (n * 16 + coh * 8) * POOL3 + pd * 225 + ph * 15 + pw;
    #pragma unroll
    for (int c8 = 0; c8 < 8; ++c8) pool[ob + c8 * POOL3] = acc[c8];
}

// ---------- 3D autocorrelation A3[pair][dd][dh][dw], full-support ----------
__global__ __launch_bounds__(256, 4) void autocorr3d(
    const float* __restrict__ x, float* __restrict__ A3p, float* __restrict__ X3p) {
    const int bx = blockIdx.x;          // 27 = pd9*3 + (dd+1)
    const int n  = blockIdx.y;
    const int pd9 = bx / 3, dd = bx % 3 - 1;
    const int ci = pd9 / 3, cj = pd9 % 3;
    const int tid = threadIdx.x;
    const int id = tid >> 3, ihc = tid & 7;
    const float* bi = x + (size_t)n * NS + ci * I3 + id * 1024;
    const int idj = id + dd;
    const bool vd = ((unsigned)idj < 32u);
    const float* bj = x + (size_t)n * NS + cj * I3 + idj * 1024;
    const bool dodiag = (ci == cj) && (dd == 0);

    float acc[3][3] = {};
    float xs = 0.f;
    #pragma unroll
    for (int r = 0; r < 4; ++r) {
        const int ih = ihc + r * 8;
        float own[32];
        #pragma unroll
        for (int q = 0; q < 8; ++q) {
            const float4 f = *reinterpret_cast<const float4*>(bi + ih * 32 + q * 4);
            own[q * 4 + 0] = f.x; own[q * 4 + 1] = f.y;
            own[q * 4 + 2] = f.z; own[q * 4 + 3] = f.w;
        }
        if (dodiag) {
            #pragma unroll
            for (int v = 0; v < 32; ++v) xs += own[v];
        }
        if (vd) {
            #pragma unroll
            for (int dh = -1; dh <= 1; ++dh) {
                const int ihj = ih + dh;
                if ((unsigned)ihj < 32u) {
                    float nb[32];
                    #pragma unroll
                    for (int q = 0; q < 8; ++q) {
                        const float4 f = *reinterpret_cast<const float4*>(bj + ihj * 32 + q * 4);
                        nb[q * 4 + 0] = f.x; nb[q * 4 + 1] = f.y;
                        nb[q * 4 + 2] = f.z; nb[q * 4 + 3] = f.w;
                    }
                    float a0 = 0.f, a1 = 0.f, a2 = 0.f;
                    #pragma unroll
                    for (int v = 0; v < 32; ++v) a1 = fmaf(own[v], nb[v], a1);
                    #pragma unroll
                    for (int v = 0; v < 31; ++v) a2 = fmaf(own[v], nb[v + 1], a2);
                    #pragma unroll
                    for (int v = 1; v < 32; ++v) a0 = fmaf(own[v], nb[v - 1], a0);
                    acc[dh + 1][0] += a0; acc[dh + 1][1] += a1; acc[dh + 1][2] += a2;
                }
            }
        }
    }
    #pragma unroll
    for (int m = 1; m < 64; m <<= 1) {
        #pragma unroll
        for (int a = 0; a < 3; ++a)
            #pragma unroll
            for (int b = 0; b < 3; ++b)
                acc[a][b] += __shfl_xor(acc[a][b], m, 64);
        xs += __shfl_xor(xs, m, 64);
    }
    __shared__ float red[4][10];
    const int wave = tid >> 6, lane = tid & 63;
    if (lane == 0) {
        #pragma unroll
        for (int a = 0; a < 3; ++a)
            #pragma unroll
            for (int b = 0; b < 3; ++b) red[wave][a * 3 + b] = acc[a][b];
        red[wave][9] = xs;
    }
    __syncthreads();
    if (tid < 9)
        A3p[(bx * 9 + tid) * 32 + n] = red[0][tid] + red[1][tid] + red[2][tid] + red[3][tid];
    if (dodiag && tid == 9)
        X3p[ci * 32 + n] = red[0][9] + red[1][9] + red[2][9] + red[3][9];
}

// ---------- face (2D) autocorrs, LDS-staged; per-n partials (deterministic) ----------
__global__ __launch_bounds__(256, 2) void faces_k2(
    const float* __restrict__ x, float* __restrict__ A2P, float* __restrict__ X2P) {
    const int f = blockIdx.x;           // 0..5
    const int n = blockIdx.y;           // 0..31
    const int s = f >> 1, e = (f & 1) ? 31 : 0;
    int su, sv, off;
    if (s == 0)      { su = 32;   sv = 1;  off = e * 1024; }  // u=h, v=w
    else if (s == 1) { su = 1024; sv = 1;  off = e * 32;   }  // u=d, v=w
    else             { su = 1024; sv = 32; off = e;        }  // u=d, v=h
    const int tid = threadIdx.x;
    __shared__ float pl[3][32][33];
    const float* xb = x + (size_t)n * NS + off;
    for (int idx = tid; idx < 3072; idx += 256) {
        const int ci = idx >> 10, r = idx & 1023, u = r >> 5, v = r & 31;
        pl[ci][u][v] = xb[ci * I3 + u * su + v * sv];
    }
    __syncthreads();
    if (tid < 81) {
        const int p = tid / 9, lag = tid % 9;
        const int du = lag / 3 - 1, dv = lag % 3 - 1;
        const int ci = p / 3, cj = p % 3;
        const int ulo = (du == -1) ? 1 : 0, uhi = (du == 1) ? 30 : 31;
        const int vlo = (dv == -1) ? 1 : 0, vhi = (dv == 1) ? 30 : 31;
        float a = 0.f;
        for (int u = ulo; u <= uhi; ++u) {
            const float* ro = &pl[ci][u][0];
            const float* rn = &pl[cj][u + du][dv];
            float t0 = 0.f, t1 = 0.f;
            for (int v = vlo; v + 1 <= vhi; v += 2) {
                t0 = fmaf(ro[v], rn[v], t0);
                t1 = fmaf(ro[v + 1], rn[v + 1], t1);
            }
            if (((vhi - vlo) & 1) == 0) t0 = fmaf(ro[vhi], rn[vhi], t0);
            a += t0 + t1;
        }
        A2P[(f * 81 + tid) * 32 + n] = a;
    } else if (tid < 84) {
        const int ci = tid - 81;
        float a = 0.f;
        for (int u = 0; u < 32; ++u)
            for (int v = 0; v < 32; ++v) a += pl[ci][u][v];
        X2P[(f * 3 + ci) * 32 + n] = a;
    }
}

// ---------- edge (1D) autocorrs, LDS-staged, all n in-block ----------
__global__ __launch_bounds__(256, 2) void edges_k2(
    const float* __restrict__ x, float* __restrict__ A1, float* __restrict__ X1) {
    const int e12 = blockIdx.x;         // 0..11
    const int dp = e12 >> 2;
    const int e1 = ((e12 >> 1) & 1) ? 31 : 0, e2 = (e12 & 1) ? 31 : 0;
    int st, off;
    if (dp == 0)      { st = 1;    off = e1 * 1024 + e2 * 32; } // free w
    else if (dp == 1) { st = 32;   off = e1 * 1024 + e2;      } // free h
    else              { st = 1024; off = e1 * 32 + e2;        } // free d
    const int tid = threadIdx.x;
    __shared__ float el[3][32][33];     // [ci][n][v]
    for (int idx = tid; idx < 3072; idx += 256) {
        const int ci = idx >> 10, r = idx & 1023, n = r >> 5, v = r & 31;
        el[ci][n][v] = x[(size_t)n * NS + ci * I3 + off + v * st];
    }
    __syncthreads();
    if (tid < 27) {
        const int p = tid / 3, DT = tid % 3, dt = DT - 1;
        const int ci = p / 3, cj = p % 3;
        const int vlo = (dt == -1) ? 1 : 0, vhi = (dt == 1) ? 30 : 31;
        float a = 0.f;
        for (int n2 = 0; n2 < 32; ++n2) {
            float t0 = 0.f;
            for (int v = vlo; v <= vhi; ++v)
                t0 = fmaf(el[ci][n2][v], el[cj][n2][v + dt], t0);
            a += t0;
        }
        A1[e12 * 27 + tid] = a;
    } else if (tid < 30) {
        const int ci = tid - 27;
        float a = 0.f;
        for (int n2 = 0; n2 < 32; ++n2)
            for (int v = 0; v < 32; ++v) a += el[ci][n2][v];
        X1[e12 * 3 + ci] = a;
    }
}

// ---------- finalize: combine A's with weight-pair sums -> ab ----------
__global__ __launch_bounds__(256) void finalize2(
    const float* __restrict__ x, const float* __restrict__ w,
    const float* __restrict__ gamma, const float* __restrict__ beta,
    const float* __restrict__ ws, float* __restrict__ ab) {
    const int tid = threadIdx.x;
    __shared__ float lw[1296];
    __shared__ float lA3[243], lX3[3], lA2[486], lX2[18], lA1[324], lX1[36];
    __shared__ float lxc[8][3][32];
    __shared__ float lA0[72], lX0[24];
    __shared__ float red2[144], red1[48];

    for (int i = tid; i < 1296; i += 256) lw[i] = w[i];
    for (int i = tid; i < 243; i += 256) {
        const float* p = ws + WS_A3P + i * 32;
        float s = 0.f;
        #pragma unroll
        for (int nn = 0; nn < 32; ++nn) s += p[nn];
        lA3[i] = s;
    }
    if (tid < 3) {
        float s = 0.f;
        for (int nn = 0; nn < 32; ++nn) s += ws[WS_X3P + tid * 32 + nn];
        lX3[tid] = s;
    }
    for (int i = tid; i < 486; i += 256) {
        const float* p = ws + WS_A2P + i * 32;
        float s = 0.f;
        #pragma unroll
        for (int nn = 0; nn < 32; ++nn) s += p[nn];
        lA2[i] = s;
    }
    if (tid < 18) {
        const float* p = ws + WS_X2P + tid * 32;
        float s = 0.f;
        for (int nn = 0; nn < 32; ++nn) s += p[nn];
        lX2[tid] = s;
    }
    for (int i = tid; i < 324; i += 256) lA1[i] = ws[WS_A1 + i];
    if (tid < 36) lX1[tid] = ws[WS_X1 + tid];
    for (int i = tid; i < 768; i += 256) {
        const int c = i / 96, ci = (i / 32) % 3, nn = i % 32;
        const int off = (((c >> 2) & 1) ? 31 : 0) * 1024 +
                        (((c >> 1) & 1) ? 31 : 0) * 32 + ((c & 1) ? 31 : 0);
        lxc[c][ci][nn] = x[(size_t)nn * NS + ci * I3 + off];
    }
    __syncthreads();
    if (tid < 72) {
        const int c = tid / 9, p = tid % 9, ci = p / 3, cj = p % 3;
        float s = 0.f;
        for (int nn = 0; nn < 32; ++nn) s += lxc[c][ci][nn] * lxc[c][cj][nn];
        lA0[tid] = s;
    }
    if (tid >= 72 && tid < 96) {
        const int t = tid - 72, c = t / 3, ci = t % 3;
        float s = 0.f;
        for (int nn = 0; nn < 32; ++nn) s += lxc[c][ci][nn];
        lX0[t] = s;
    }
    __syncthreads();

    // valid-k pairs (k, k') per delta index 0..2 (cj displaced by d = idx-1)
    const int KPn[3] = {1, 3, 1};
    const int KPa[3][3] = {{0, 0, 0}, {0, 1, 2}, {2, 0, 0}};
    const int KPb[3][3] = {{2, 0, 0}, {0, 1, 2}, {0, 0, 0}};

    if (tid < 144) {   // quadratic: per (co, ordered ci-pair)
        const int co = tid / 9, p = tid % 9, ci = p / 3, cj = p % 3;
        const float* wi = lw + (ci * 16 + co) * 27;
        const float* wj = lw + (cj * 16 + co) * 27;
        float tot = 0.f;
        for (int dd = 0; dd < 3; ++dd)
            for (int dh = 0; dh < 3; ++dh)
                for (int dw = 0; dw < 3; ++dw) {
                    float sw = 0.f;
                    for (int a = 0; a < KPn[dd]; ++a)
                        for (int b = 0; b < KPn[dh]; ++b)
                            for (int c = 0; c < KPn[dw]; ++c)
                                sw += wi[KPa[dd][a] * 9 + KPa[dh][b] * 3 + KPa[dw][c]] *
                                      wj[KPb[dd][a] * 9 + KPb[dh][b] * 3 + KPb[dw][c]];
                    tot += lA3[p * 27 + dd * 9 + dh * 3 + dw] * sw;
                }
        for (int f = 0; f < 6; ++f) {
            const int s = f >> 1, c = (f & 1) ? 2 : 0;
            float fsum = 0.f;
            for (int du = 0; du < 3; ++du)
                for (int dv = 0; dv < 3; ++dv) {
                    float sw = 0.f;
                    for (int a = 0; a < KPn[du]; ++a)
                        for (int b = 0; b < KPn[dv]; ++b) {
                            const int ku = KPa[du][a], kup = KPb[du][a];
                            const int kv = KPa[dv][b], kvp = KPb[dv][b];
                            int ii, jj;
                            if (s == 0)      { ii = c * 9 + ku * 3 + kv;  jj = c * 9 + kup * 3 + kvp; }
                            else if (s == 1) { ii = ku * 9 + c * 3 + kv;  jj = kup * 9 + c * 3 + kvp; }
                            else             { ii = ku * 9 + kv * 3 + c;  jj = kup * 9 + kvp * 3 + c; }
                            sw += wi[ii] * wj[jj];
                        }
                    fsum += lA2[(f * 9 + p) * 9 + du * 3 + dv] * sw;
                }
            tot -= fsum;
        }
        for (int e12 = 0; e12 < 12; ++e12) {
            const int dp = e12 >> 2;
            const int c1 = ((e12 >> 1) & 1) ? 2 : 0, c2 = (e12 & 1) ? 2 : 0;
            float esum = 0.f;
            for (int dt = 0; dt < 3; ++dt) {
                float sw = 0.f;
                for (int a = 0; a < KPn[dt]; ++a) {
                    const int kt = KPa[dt][a], ktp = KPb[dt][a];
                    int ii, jj;
                    if (dp == 0)      { ii = c1 * 9 + c2 * 3 + kt; jj = c1 * 9 + c2 * 3 + ktp; }
                    else if (dp == 1) { ii = c1 * 9 + kt * 3 + c2; jj = c1 * 9 + ktp * 3 + c2; }
                    else              { ii = kt * 9 + c1 * 3 + c2; jj = ktp * 9 + c1 * 3 + c2; }
                    sw += wi[ii] * wj[jj];
                }
                esum += lA1[(e12 * 9 + p) * 3 + dt] * sw;
            }
            tot += esum;
        }
        for (int c = 0; c < 8; ++c) {
            const int kk = (((c >> 2) & 1) ? 2 : 0) * 9 +
                           (((c >> 1) & 1) ? 2 : 0) * 3 + ((c & 1) ? 2 : 0);
            tot -= lA0[c * 9 + p] * wi[kk] * wj[kk];
        }
        red2[tid] = tot;
    }
    if (tid >= 144 && tid < 192) {   // linear: per (co, ci)
        const int t = tid - 144, co = t / 3, ci = t % 3;
        const float* wi = lw + (ci * 16 + co) * 27;
        float lw3 = 0.f;
        for (int k = 0; k < 27; ++k) lw3 += wi[k];
        float tot = lX3[ci] * lw3;
        for (int f = 0; f < 6; ++f) {
            const int s = f >> 1, c = (f & 1) ? 2 : 0;
            float l2 = 0.f;
            for (int ku = 0; ku < 3; ++ku)
                for (int kv = 0; kv < 3; ++kv) {
                    const int ii = (s == 0) ? c * 9 + ku * 3 + kv
                                 : (s == 1) ? ku * 9 + c * 3 + kv
                                            : ku * 9 + kv * 3 + c;
                    l2 += wi[ii];
                }
            tot -= lX2[f * 3 + ci] * l2;
        }
        for (int e12 = 0; e12 < 12; ++e12) {
            const int dp = e12 >> 2;
            const int c1 = ((e12 >> 1) & 1) ? 2 : 0, c2 = (e12 & 1) ? 2 : 0;
            float l1 = 0.f;
            for (int kt = 0; kt < 3; ++kt) {
                const int ii = (dp == 0) ? c1 * 9 + c2 * 3 + kt
                             : (dp == 1) ? c1 * 9 + kt * 3 + c2
                                         : kt * 9 + c1 * 3 + c2;
                l1 += wi[ii];
            }
            tot += lX1[e12 * 3 + ci] * l1;
        }
        for (int c = 0; c < 8; ++c) {
            const int kk = (((c >> 2) & 1) ? 2 : 0) * 9 +
                           (((c >> 1) & 1) ? 2 : 0) * 3 + ((c & 1) ? 2 : 0);
            tot -= lX0[c * 3 + ci] * wi[kk];
        }
        red1[t] = tot;
    }
    __syncthreads();
    if (tid < 16) {
        float S2 = 0.f;
        for (int p = 0; p < 9; ++p) S2 += red2[tid * 9 + p];
        const float S1 = red1[tid * 3] + red1[tid * 3 + 1] + red1[tid * 3 + 2];
        const float mean = S1 / COUNT_Y;
        const float var = S2 / COUNT_Y - mean * mean;
        const float invg = rsqrtf(var + 1e-5f) * gamma[tid];
        ab[tid] = invg * (1.0f / 64.0f);
        ab[16 + tid] = beta[tid] - mean * invg;
    }
}

__global__ __launch_bounds__(256) void apply_norm(
    float* __restrict__ out, const float* __restrict__ ab) {
    const int base = (blockIdx.x * 256 + threadIdx.x) * 4;
    if (base >= TOTAL_OUT) return;
    float4 v = *reinterpret_cast<float4*>(out + base);
    float r[4] = {v.x, v.y, v.z, v.w};
    #pragma unroll
    for (int j = 0; j < 4; ++j) {
        const int c = ((base + j) / POOL3) & 15;
        r[j] = fmaf(r[j], ab[c], ab[16 + c]);
    }
    *reinterpret_cast<float4*>(out + base) = make_float4(r[0], r[1], r[2], r[3]);
}

extern "C" void kernel_launch(void* const* d_in, const int* in_sizes, int n_in,
                              void* d_out, int out_size, void* d_ws, size_t ws_size,
                              hipStream_t stream) {
    const float* x     = (const float*)d_in[0];
    const float* w     = (const float*)d_in[1];
    const float* gamma = (const float*)d_in[2];
    const float* beta  = (const float*)d_in[3];
    float* out = (float*)d_out;
    float* ws  = (float*)d_ws;

    prep_G<<<6, 256, 0, stream>>>(w, ws + WS_G);
    pooled_conv<<<dim3(30, 32), 256, 0, stream>>>(x, ws + WS_G, out);
    autocorr3d<<<dim3(27, 32), 256, 0, stream>>>(x, ws + WS_A3P, ws + WS_X3P);
    faces_k2<<<dim3(6, 32), 256, 0, stream>>>(x, ws + WS_A2P, ws + WS_X2P);
    edges_k2<<<12, 256, 0, stream>>>(x, ws + WS_A1, ws + WS_X1);
    finalize2<<<1, 256, 0, stream>>>(x, w, gamma, beta, ws, ws + WS_AB);
    apply_norm<<<(TOTAL_OUT / 4 + 255) / 256, 256, 0, stream>>>(out, ws + WS_AB);
}